// Round 1
// baseline (5149.460 us; speedup 1.0000x reference)
//
#include <hip/hip_runtime.h>
#include <math.h>

// Problem constants
// B=32, T=12, N=2048, C=1, D=10, K=2, H=32
// CH = C+H = 33, COLS = B*CH = 1056, padded to COLP = 1088 (=17*64)

#define NNODE 2048
#define NB 32
#define NT 12
#define NH 32
#define CH 33
#define COLS 1056
#define COLP 1088
#define ND 10

// ---------------- workspace layout (in floats) ----------------
constexpr size_t OFF_A   = 0;                         // A: 2048*2048
constexpr size_t OFF_WG  = OFF_A  + 2048u*2048u;      // Wg: 2048*2*33*64 = 8650752
constexpr size_t OFF_WU  = OFF_WG + 8650752u;         // Wu: 2048*2*33*32 = 4325376
constexpr size_t OFF_BG  = OFF_WU + 4325376u;         // bg: 2048*64
constexpr size_t OFF_BU  = OFF_BG + 131072u;          // bu: 2048*32
constexpr size_t OFF_XS  = OFF_BU + 65536u;           // Xs: 2048*1088
constexpr size_t OFF_XS2 = OFF_XS + 2228224u;         // Xs2: 2048*1088
constexpr size_t OFF_Y   = OFF_XS2 + 2228224u;        // Y: 2048*1088
constexpr size_t OFF_R   = OFF_Y  + 2228224u;         // rbuf: 2048*1024
// total = 26,148,864 floats = ~104.6 MB

// ---------------- A = softmax(relu(E E^T), axis=1) ----------------
__global__ __launch_bounds__(256) void adj_kernel(const float* __restrict__ E,
                                                  float* __restrict__ A) {
    __shared__ float En[ND];
    __shared__ float red[256];
    const int n = blockIdx.x;
    const int t = threadIdx.x;
    if (t < ND) En[t] = E[n * ND + t];
    __syncthreads();
    float v[8];
    float mx = 0.f;
#pragma unroll
    for (int i = 0; i < 8; ++i) {
        const int m = t + i * 256;
        float acc = 0.f;
#pragma unroll
        for (int d = 0; d < ND; ++d) acc += En[d] * E[m * ND + d];
        acc = fmaxf(acc, 0.f);
        v[i] = acc;
        mx = fmaxf(mx, acc);
    }
    red[t] = mx;
    __syncthreads();
    for (int s = 128; s > 0; s >>= 1) {
        if (t < s) red[t] = fmaxf(red[t], red[t + s]);
        __syncthreads();
    }
    mx = red[0];
    __syncthreads();
    float sum = 0.f;
#pragma unroll
    for (int i = 0; i < 8; ++i) {
        v[i] = expf(v[i] - mx);
        sum += v[i];
    }
    red[t] = sum;
    __syncthreads();
    for (int s = 128; s > 0; s >>= 1) {
        if (t < s) red[t] += red[t + s];
        __syncthreads();
    }
    const float inv = 1.f / red[0];
#pragma unroll
    for (int i = 0; i < 8; ++i) A[(size_t)n * NNODE + t + i * 256] = v[i] * inv;
}

// ---------------- per-node weights: Wg[n,k,i,o] = sum_d E[n,d] gW[d,k,i,o] ----------------
__global__ __launch_bounds__(256) void wg_kernel(const float* __restrict__ E,
                                                 const float* __restrict__ gW,
                                                 float* __restrict__ Wg) {
    const int idx = blockIdx.x * 256 + threadIdx.x;
    if (idx >= NNODE * 4224) return;
    const int n = idx / 4224, rem = idx % 4224;
    float acc = 0.f;
#pragma unroll
    for (int d = 0; d < ND; ++d) acc += E[n * ND + d] * gW[d * 4224 + rem];
    Wg[idx] = acc;
}

__global__ __launch_bounds__(256) void wu_kernel(const float* __restrict__ E,
                                                 const float* __restrict__ uW,
                                                 float* __restrict__ Wu) {
    const int idx = blockIdx.x * 256 + threadIdx.x;
    if (idx >= NNODE * 2112) return;
    const int n = idx / 2112, rem = idx % 2112;
    float acc = 0.f;
#pragma unroll
    for (int d = 0; d < ND; ++d) acc += E[n * ND + d] * uW[d * 2112 + rem];
    Wu[idx] = acc;
}

__global__ __launch_bounds__(256) void bias_kernel(const float* __restrict__ E,
                                                   const float* __restrict__ gb,
                                                   const float* __restrict__ ub,
                                                   float* __restrict__ bg,
                                                   float* __restrict__ bu) {
    const int idx = blockIdx.x * 256 + threadIdx.x;
    if (idx < NNODE * 64) {
        const int n = idx >> 6, o = idx & 63;
        float acc = 0.f;
#pragma unroll
        for (int d = 0; d < ND; ++d) acc += E[n * ND + d] * gb[d * 64 + o];
        bg[idx] = acc;
    } else if (idx < NNODE * 64 + NNODE * 32) {
        const int j = idx - NNODE * 64;
        const int n = j >> 5, o = j & 31;
        float acc = 0.f;
#pragma unroll
        for (int d = 0; d < ND; ++d) acc += E[n * ND + d] * ub[d * 32 + o];
        bu[j] = acc;
    }
}

// ---------------- init Xs: col0 of each b = x_0, h cols = 0, pad = 0 ----------------
__global__ __launch_bounds__(256) void setup_kernel(const float* __restrict__ src,
                                                    float* __restrict__ Xs) {
    const int idx = blockIdx.x * 256 + threadIdx.x;
    if (idx >= NNODE * COLP) return;
    const int n = idx / COLP, c = idx % COLP;
    float v = 0.f;
    if (c < COLS && (c % CH) == 0) {
        const int b = c / CH;
        v = src[(size_t)b * NT * NNODE + n];  // t = 0
    }
    Xs[idx] = v;
}

// ---------------- Y = A @ X   (A: [2048,2048], X/Y: [2048, 1088]) ----------------
#define BM 64
#define BN 64
#define BK 16

__global__ __launch_bounds__(256) void mm_kernel(const float* __restrict__ A,
                                                 const float* __restrict__ X,
                                                 float* __restrict__ Y) {
    __shared__ float As[BK][68];   // padded: 68%4==0 keeps b128 alignment, 2-way banks only
    __shared__ float Bs[BK][BN];
    const int t = threadIdx.x;
    const int row0 = blockIdx.y * BM;
    const int col0 = blockIdx.x * BN;
    const int tx = t & 15, ty = t >> 4;
    const int arow = t >> 4;   // 0..15
    const int akcol = t & 15;  // 0..15
    const int bk = t >> 6;     // 0..3
    const int bc = t & 63;
    float acc[4][4] = {};
    for (int kt = 0; kt < NNODE; kt += BK) {
#pragma unroll
        for (int i = 0; i < 4; ++i)
            As[akcol][arow + i * 16] =
                A[(size_t)(row0 + arow + i * 16) * NNODE + kt + akcol];
#pragma unroll
        for (int i = 0; i < 4; ++i)
            Bs[bk + i * 4][bc] = X[(size_t)(kt + bk + i * 4) * COLP + col0 + bc];
        __syncthreads();
#pragma unroll
        for (int k = 0; k < BK; ++k) {
            float a[4], b[4];
#pragma unroll
            for (int i = 0; i < 4; ++i) a[i] = As[k][ty * 4 + i];
#pragma unroll
            for (int j = 0; j < 4; ++j) b[j] = Bs[k][tx * 4 + j];
#pragma unroll
            for (int i = 0; i < 4; ++i)
#pragma unroll
                for (int j = 0; j < 4; ++j) acc[i][j] += a[i] * b[j];
        }
        __syncthreads();
    }
#pragma unroll
    for (int i = 0; i < 4; ++i)
#pragma unroll
        for (int j = 0; j < 4; ++j)
            Y[(size_t)(row0 + ty * 4 + i) * COLP + col0 + tx * 4 + j] = acc[i][j];
}

// ---------------- gate: zr = sigmoid(per-node W applied to [Xs | A@Xs]) ----------------
// writes Xs2 (= [xt, z*h]) and rbuf
__global__ __launch_bounds__(256) void gate_kernel(const float* __restrict__ Xs,
                                                   const float* __restrict__ Y,
                                                   const float* __restrict__ Wg,
                                                   const float* __restrict__ bg,
                                                   float* __restrict__ Xs2,
                                                   float* __restrict__ rbuf) {
    __shared__ float Wgs[4224];
    __shared__ float xrow[COLS];
    __shared__ float yrow[COLS];
    const int n = blockIdx.x;
    const int t = threadIdx.x;
    for (int i = t; i < 4224; i += 256) Wgs[i] = Wg[(size_t)n * 4224 + i];
    for (int i = t; i < COLS; i += 256) {
        xrow[i] = Xs[(size_t)n * COLP + i];
        yrow[i] = Y[(size_t)n * COLP + i];
    }
    __syncthreads();
    const int o = t & 63;
    const int b0 = t >> 6;  // 0..3 (uniform per wave)
#pragma unroll
    for (int bi = 0; bi < 8; ++bi) {
        const int b = b0 + bi * 4;
        float acc = bg[n * 64 + o];
        const float* xr = xrow + b * CH;
        const float* yr = yrow + b * CH;
#pragma unroll
        for (int i = 0; i < CH; ++i) {
            acc += xr[i] * Wgs[i * 64 + o];
            acc += yr[i] * Wgs[2112 + i * 64 + o];
        }
        const float s = 1.f / (1.f + expf(-acc));
        if (o < 32) {
            const float hold = xr[1 + o];
            Xs2[(size_t)n * COLP + b * CH + 1 + o] = s * hold;
            if (o == 0) Xs2[(size_t)n * COLP + b * CH] = xr[0];
        } else {
            rbuf[(size_t)n * 1024 + b * 32 + (o - 32)] = s;
        }
    }
}

// ---------------- update: hc = tanh(...), hnew = r*h + (1-r)*hc; stage x_{t+1} ----------------
__global__ __launch_bounds__(256) void upd_kernel(const float* __restrict__ Xs2,
                                                  const float* __restrict__ Y,
                                                  const float* __restrict__ Wu,
                                                  const float* __restrict__ bu,
                                                  const float* __restrict__ rbuf,
                                                  const float* __restrict__ src,
                                                  float* __restrict__ Xs, int tnext) {
    __shared__ float Wus[2112];
    __shared__ float xrow[COLS];
    __shared__ float yrow[COLS];
    const int n = blockIdx.x;
    const int t = threadIdx.x;
    for (int i = t; i < 2112; i += 256) Wus[i] = Wu[(size_t)n * 2112 + i];
    for (int i = t; i < COLS; i += 256) {
        xrow[i] = Xs2[(size_t)n * COLP + i];
        yrow[i] = Y[(size_t)n * COLP + i];
    }
    __syncthreads();
    const int o = t & 31;
    const int b0 = t >> 5;  // 0..7
#pragma unroll
    for (int bi = 0; bi < 4; ++bi) {
        const int b = b0 + bi * 8;
        float acc = bu[n * 32 + o];
        const float* xr = xrow + b * CH;
        const float* yr = yrow + b * CH;
#pragma unroll
        for (int i = 0; i < CH; ++i) {
            acc += xr[i] * Wus[i * 32 + o];
            acc += yr[i] * Wus[1056 + i * 32 + o];
        }
        const float hc = tanhf(acc);
        const float r = rbuf[(size_t)n * 1024 + b * 32 + o];
        const size_t hidx = (size_t)n * COLP + b * CH + 1 + o;
        const float hold = Xs[hidx];
        Xs[hidx] = r * hold + (1.f - r) * hc;
        if (o == 0 && tnext < NT)
            Xs[(size_t)n * COLP + b * CH] =
                src[(size_t)b * NT * NNODE + (size_t)tnext * NNODE + n];
    }
}

// ---------------- out[b,0,n,t] = dot(h[b,n,:], convW[t,:]) + convb[t] ----------------
__global__ __launch_bounds__(256) void out_kernel(const float* __restrict__ Xs,
                                                  const float* __restrict__ cw,
                                                  const float* __restrict__ cb,
                                                  float* __restrict__ out) {
    __shared__ float h[NB * NH];    // [b][j]
    __shared__ float cws[NT * NH];  // [t][j]
    __shared__ float cbs[NT];
    const int n = blockIdx.x;
    const int t = threadIdx.x;
    for (int i = t; i < NT * NH; i += 256) cws[i] = cw[i];
    if (t < NT) cbs[t] = cb[t];
    for (int i = t; i < NB * NH; i += 256) {
        const int b = i >> 5, j = i & 31;
        h[i] = Xs[(size_t)n * COLP + b * CH + 1 + j];
    }
    __syncthreads();
    for (int p = t; p < NB * NT; p += 256) {
        const int b = p / NT, tt = p % NT;
        float acc = cbs[tt];
#pragma unroll
        for (int j = 0; j < NH; ++j) acc += h[b * NH + j] * cws[tt * NH + j];
        out[(size_t)b * NNODE * NT + (size_t)n * NT + tt] = acc;
    }
}

extern "C" void kernel_launch(void* const* d_in, const int* in_sizes, int n_in,
                              void* d_out, int out_size, void* d_ws, size_t ws_size,
                              hipStream_t stream) {
    const float* src  = (const float*)d_in[0];  // [32,12,2048,1]
    const float* E    = (const float*)d_in[1];  // [2048,10]
    const float* gW   = (const float*)d_in[2];  // [10,2,33,64]
    const float* gb   = (const float*)d_in[3];  // [10,64]
    const float* uW   = (const float*)d_in[4];  // [10,2,33,32]
    const float* ub   = (const float*)d_in[5];  // [10,32]
    const float* cw   = (const float*)d_in[6];  // [12,1,1,32]
    const float* cb   = (const float*)d_in[7];  // [12]
    float* out = (float*)d_out;

    float* ws  = (float*)d_ws;
    float* A   = ws + OFF_A;
    float* Wg  = ws + OFF_WG;
    float* Wu  = ws + OFF_WU;
    float* bg  = ws + OFF_BG;
    float* bu  = ws + OFF_BU;
    float* Xs  = ws + OFF_XS;
    float* Xs2 = ws + OFF_XS2;
    float* Y   = ws + OFF_Y;
    float* rb  = ws + OFF_R;

    adj_kernel<<<NNODE, 256, 0, stream>>>(E, A);
    wg_kernel<<<(NNODE * 4224 + 255) / 256, 256, 0, stream>>>(E, gW, Wg);
    wu_kernel<<<(NNODE * 2112 + 255) / 256, 256, 0, stream>>>(E, uW, Wu);
    bias_kernel<<<(NNODE * 96 + 255) / 256, 256, 0, stream>>>(E, gb, ub, bg, bu);
    setup_kernel<<<(NNODE * COLP + 255) / 256, 256, 0, stream>>>(src, Xs);

    const dim3 mmgrid(COLP / BN, NNODE / BM);
    for (int t = 0; t < NT; ++t) {
        mm_kernel<<<mmgrid, 256, 0, stream>>>(A, Xs, Y);
        gate_kernel<<<NNODE, 256, 0, stream>>>(Xs, Y, Wg, bg, Xs2, rb);
        mm_kernel<<<mmgrid, 256, 0, stream>>>(A, Xs2, Y);
        upd_kernel<<<NNODE, 256, 0, stream>>>(Xs2, Y, Wu, bu, rb, src, Xs, t + 1);
    }
    out_kernel<<<NNODE, 256, 0, stream>>>(Xs, cw, cb, out);
}

// Round 3
// 2524.995 us; speedup vs baseline: 2.0394x; 2.0394x over previous
//
#include <hip/hip_runtime.h>
#include <hip/hip_bf16.h>
#include <math.h>

// Problem constants
// B=32, T=12, N=2048, C=1, D=10, K=2, H=32
// CH = C+H = 33, COLS = B*CH = 1056, padded to COLP = 1152 (=9*128)

#define NNODE 2048
#define NB 32
#define NT 12
#define NH 32
#define CH 33
#define COLS 1056
#define COLP 1152
#define ND 10

// A is stored fp16 pre-scaled by ASCALE (power of 2, exact) to keep softmax
// tail entries out of fp16-denormal range; mm epilogue multiplies by 1/ASCALE.
#define ASCALE 256.0f
#define AINV 0.00390625f

typedef _Float16 half8 __attribute__((ext_vector_type(8)));
typedef float floatx4 __attribute__((ext_vector_type(4)));

// ---------------- workspace layout (in float slots) ----------------
constexpr size_t OFF_AH  = 0;                          // Ah fp16: 2048*2048 halfs = 2,097,152 floats
constexpr size_t OFF_WG  = OFF_AH + 2097152u;          // Wg: 2048*2*33*64 = 8650752
constexpr size_t OFF_WU  = OFF_WG + 8650752u;          // Wu: 2048*2*33*32 = 4325376
constexpr size_t OFF_BG  = OFF_WU + 4325376u;          // bg: 2048*64
constexpr size_t OFF_BU  = OFF_BG + 131072u;           // bu: 2048*32
constexpr size_t OFF_XS  = OFF_BU + 65536u;            // Xs:  2048*1152
constexpr size_t OFF_XS2 = OFF_XS + 2359296u;          // Xs2: 2048*1152
constexpr size_t OFF_Y   = OFF_XS2 + 2359296u;         // Y:   2048*1152
constexpr size_t OFF_R   = OFF_Y + 2359296u;           // rbuf: 2048*1024
// end = OFF_R + 2097152 = 24,444,928 floats = ~97.8 MB

static __device__ __forceinline__ unsigned short f2h(float f) {
    _Float16 h = (_Float16)f;
    return *(unsigned short*)&h;
}

// ---------------- A = softmax(relu(E E^T), axis=1) * ASCALE, stored fp16 ----------------
__global__ __launch_bounds__(256) void adj_kernel(const float* __restrict__ E,
                                                  _Float16* __restrict__ Ah) {
    __shared__ float En[ND];
    __shared__ float red[256];
    const int n = blockIdx.x;
    const int t = threadIdx.x;
    if (t < ND) En[t] = E[n * ND + t];
    __syncthreads();
    float v[8];
    float mx = 0.f;
#pragma unroll
    for (int i = 0; i < 8; ++i) {
        const int m = t + i * 256;
        float acc = 0.f;
#pragma unroll
        for (int d = 0; d < ND; ++d) acc += En[d] * E[m * ND + d];
        acc = fmaxf(acc, 0.f);
        v[i] = acc;
        mx = fmaxf(mx, acc);
    }
    red[t] = mx;
    __syncthreads();
    for (int s = 128; s > 0; s >>= 1) {
        if (t < s) red[t] = fmaxf(red[t], red[t + s]);
        __syncthreads();
    }
    mx = red[0];
    __syncthreads();
    float sum = 0.f;
#pragma unroll
    for (int i = 0; i < 8; ++i) {
        v[i] = expf(v[i] - mx);
        sum += v[i];
    }
    red[t] = sum;
    __syncthreads();
    for (int s = 128; s > 0; s >>= 1) {
        if (t < s) red[t] += red[t + s];
        __syncthreads();
    }
    const float inv = ASCALE / red[0];
#pragma unroll
    for (int i = 0; i < 8; ++i)
        Ah[(size_t)n * NNODE + t + i * 256] = (_Float16)(v[i] * inv);
}

// ---------------- per-node weights ----------------
__global__ __launch_bounds__(256) void wg_kernel(const float* __restrict__ E,
                                                 const float* __restrict__ gW,
                                                 float* __restrict__ Wg) {
    const int idx = blockIdx.x * 256 + threadIdx.x;
    if (idx >= NNODE * 4224) return;
    const int n = idx / 4224, rem = idx % 4224;
    float acc = 0.f;
#pragma unroll
    for (int d = 0; d < ND; ++d) acc += E[n * ND + d] * gW[d * 4224 + rem];
    Wg[idx] = acc;
}

__global__ __launch_bounds__(256) void wu_kernel(const float* __restrict__ E,
                                                 const float* __restrict__ uW,
                                                 float* __restrict__ Wu) {
    const int idx = blockIdx.x * 256 + threadIdx.x;
    if (idx >= NNODE * 2112) return;
    const int n = idx / 2112, rem = idx % 2112;
    float acc = 0.f;
#pragma unroll
    for (int d = 0; d < ND; ++d) acc += E[n * ND + d] * uW[d * 2112 + rem];
    Wu[idx] = acc;
}

__global__ __launch_bounds__(256) void bias_kernel(const float* __restrict__ E,
                                                   const float* __restrict__ gb,
                                                   const float* __restrict__ ub,
                                                   float* __restrict__ bg,
                                                   float* __restrict__ bu) {
    const int idx = blockIdx.x * 256 + threadIdx.x;
    if (idx < NNODE * 64) {
        const int n = idx >> 6, o = idx & 63;
        float acc = 0.f;
#pragma unroll
        for (int d = 0; d < ND; ++d) acc += E[n * ND + d] * gb[d * 64 + o];
        bg[idx] = acc;
    } else if (idx < NNODE * 64 + NNODE * 32) {
        const int j = idx - NNODE * 64;
        const int n = j >> 5, o = j & 31;
        float acc = 0.f;
#pragma unroll
        for (int d = 0; d < ND; ++d) acc += E[n * ND + d] * ub[d * 32 + o];
        bu[j] = acc;
    }
}

// ---------------- init Xs (x cols = x_0, rest 0) and zero Xs2 ----------------
__global__ __launch_bounds__(256) void setup_kernel(const float* __restrict__ src,
                                                    float* __restrict__ Xs,
                                                    float* __restrict__ Xs2) {
    const int idx = blockIdx.x * 256 + threadIdx.x;
    if (idx >= NNODE * COLP) return;
    const int n = idx / COLP, c = idx % COLP;
    float v = 0.f;
    if (c < COLS && (c % CH) == 0) {
        const int b = c / CH;
        v = src[(size_t)b * NT * NNODE + n];  // t = 0
    }
    Xs[idx] = v;
    Xs2[idx] = 0.f;
}

// ---------------- Y = (A*ASCALE) @ X * (1/ASCALE)  via fp16 MFMA ----------------
// A: fp16 [2048][2048] row-major (k-contig). X: fp32 [2048][COLP].
// Block tile 128(m) x 128(n), BK=32. 4 waves, each 64x64 = 4x4 MFMA 16x16x32 tiles.
// LDS rows padded to 40 halfs (80B = 20 dwords): 16B-aligned b128, uniform bank spread.
__global__ __launch_bounds__(256) void mm_kernel(const _Float16* __restrict__ Ah,
                                                 const float* __restrict__ X,
                                                 float* __restrict__ Y) {
    __shared__ unsigned short As[128][40];  // [m][k]
    __shared__ unsigned short Bs[128][40];  // [n][k] (transposed X tile)
    const int t = threadIdx.x;
    const int m0 = blockIdx.y * 128;
    const int c0 = blockIdx.x * 128;
    const int lane = t & 63;
    const int w = t >> 6;
    const int wm = (w & 1) * 64;
    const int wn = (w >> 1) * 64;
    const int lm = lane & 15;  // row/col within 16-tile
    const int q = lane >> 4;   // quad -> k-offset q*8

    // A staging: thread t handles row ar, 16-half chunk pair at ac
    const int ar = t >> 1;
    const int ac = (t & 1) * 16;
    // B staging: thread t handles k rows [4*bh,4*bh+4), col pairs 2*bu(+64)
    const int bu = t & 31;
    const int bh = t >> 5;

    floatx4 acc[4][4] = {};

    for (int kt = 0; kt < NNODE; kt += 32) {
        // global loads first (let them overlap)
        const unsigned short* pa =
            (const unsigned short*)Ah + (size_t)(m0 + ar) * NNODE + kt + ac;
        uint4 a0 = *(const uint4*)pa;
        uint4 a1 = *(const uint4*)(pa + 8);
        float2 xv[4][2];
        const float* xb = X + (size_t)(kt + 4 * bh) * COLP + c0 + 2 * bu;
#pragma unroll
        for (int i = 0; i < 4; ++i) {
            xv[i][0] = *(const float2*)(xb + (size_t)i * COLP);
            xv[i][1] = *(const float2*)(xb + (size_t)i * COLP + 64);
        }
        *(uint4*)&As[ar][ac] = a0;
        *(uint4*)&As[ar][ac + 8] = a1;
#pragma unroll
        for (int j = 0; j < 2; ++j) {
#pragma unroll
            for (int cc = 0; cc < 2; ++cc) {
#pragma unroll
                for (int kp = 0; kp < 2; ++kp) {
                    const float f0 = cc ? xv[2 * kp][j].y : xv[2 * kp][j].x;
                    const float f1 = cc ? xv[2 * kp + 1][j].y : xv[2 * kp + 1][j].x;
                    const unsigned int pk =
                        (unsigned int)f2h(f0) | ((unsigned int)f2h(f1) << 16);
                    *(unsigned int*)&Bs[2 * bu + 64 * j + cc][4 * bh + 2 * kp] = pk;
                }
            }
        }
        __syncthreads();
        half8 af[4], bf[4];
#pragma unroll
        for (int mt = 0; mt < 4; ++mt)
            af[mt] = *(const half8*)&As[wm + mt * 16 + lm][q * 8];
#pragma unroll
        for (int nt = 0; nt < 4; ++nt)
            bf[nt] = *(const half8*)&Bs[wn + nt * 16 + lm][q * 8];
#pragma unroll
        for (int mt = 0; mt < 4; ++mt)
#pragma unroll
            for (int nt = 0; nt < 4; ++nt)
                acc[mt][nt] = __builtin_amdgcn_mfma_f32_16x16x32_f16(
                    af[mt], bf[nt], acc[mt][nt], 0, 0, 0);
        __syncthreads();
    }
    // epilogue: C/D layout col = lane&15, row = quad*4 + reg; undo ASCALE
#pragma unroll
    for (int mt = 0; mt < 4; ++mt) {
#pragma unroll
        for (int nt = 0; nt < 4; ++nt) {
            const int row = m0 + wm + mt * 16 + q * 4;
            const int col = c0 + wn + nt * 16 + lm;
#pragma unroll
            for (int r = 0; r < 4; ++r)
                Y[(size_t)(row + r) * COLP + col] = acc[mt][nt][r] * AINV;
        }
    }
}

// ---------------- gate: zr = sigmoid(per-node W applied to [Xs | A@Xs]) ----------------
__global__ __launch_bounds__(256) void gate_kernel(const float* __restrict__ Xs,
                                                   const float* __restrict__ Y,
                                                   const float* __restrict__ Wg,
                                                   const float* __restrict__ bg,
                                                   float* __restrict__ Xs2,
                                                   float* __restrict__ rbuf) {
    __shared__ float Wgs[4224];
    __shared__ float xrow[COLS];
    __shared__ float yrow[COLS];
    const int n = blockIdx.x;
    const int t = threadIdx.x;
    for (int i = t; i < 4224; i += 256) Wgs[i] = Wg[(size_t)n * 4224 + i];
    for (int i = t; i < COLS; i += 256) {
        xrow[i] = Xs[(size_t)n * COLP + i];
        yrow[i] = Y[(size_t)n * COLP + i];
    }
    __syncthreads();
    const int o = t & 63;
    const int b0 = t >> 6;  // 0..3
#pragma unroll
    for (int bi = 0; bi < 8; ++bi) {
        const int b = b0 + bi * 4;
        float acc = bg[n * 64 + o];
        const float* xr = xrow + b * CH;
        const float* yr = yrow + b * CH;
#pragma unroll
        for (int i = 0; i < CH; ++i) {
            acc += xr[i] * Wgs[i * 64 + o];
            acc += yr[i] * Wgs[2112 + i * 64 + o];
        }
        const float s = 1.f / (1.f + expf(-acc));
        if (o < 32) {
            const float hold = xr[1 + o];
            Xs2[(size_t)n * COLP + b * CH + 1 + o] = s * hold;
            if (o == 0) Xs2[(size_t)n * COLP + b * CH] = xr[0];
        } else {
            rbuf[(size_t)n * 1024 + b * 32 + (o - 32)] = s;
        }
    }
}

// ---------------- update ----------------
__global__ __launch_bounds__(256) void upd_kernel(const float* __restrict__ Xs2,
                                                  const float* __restrict__ Y,
                                                  const float* __restrict__ Wu,
                                                  const float* __restrict__ bu,
                                                  const float* __restrict__ rbuf,
                                                  const float* __restrict__ src,
                                                  float* __restrict__ Xs, int tnext) {
    __shared__ float Wus[2112];
    __shared__ float xrow[COLS];
    __shared__ float yrow[COLS];
    const int n = blockIdx.x;
    const int t = threadIdx.x;
    for (int i = t; i < 2112; i += 256) Wus[i] = Wu[(size_t)n * 2112 + i];
    for (int i = t; i < COLS; i += 256) {
        xrow[i] = Xs2[(size_t)n * COLP + i];
        yrow[i] = Y[(size_t)n * COLP + i];
    }
    __syncthreads();
    const int o = t & 31;
    const int b0 = t >> 5;  // 0..7
#pragma unroll
    for (int bi = 0; bi < 4; ++bi) {
        const int b = b0 + bi * 8;
        float acc = bu[n * 32 + o];
        const float* xr = xrow + b * CH;
        const float* yr = yrow + b * CH;
#pragma unroll
        for (int i = 0; i < CH; ++i) {
            acc += xr[i] * Wus[i * 32 + o];
            acc += yr[i] * Wus[1056 + i * 32 + o];
        }
        const float hc = tanhf(acc);
        const float r = rbuf[(size_t)n * 1024 + b * 32 + o];
        const size_t hidx = (size_t)n * COLP + b * CH + 1 + o;
        const float hold = Xs[hidx];
        Xs[hidx] = r * hold + (1.f - r) * hc;
        if (o == 0 && tnext < NT)
            Xs[(size_t)n * COLP + b * CH] =
                src[(size_t)b * NT * NNODE + (size_t)tnext * NNODE + n];
    }
}

// ---------------- out[b,0,n,t] = dot(h[b,n,:], convW[t,:]) + convb[t] ----------------
__global__ __launch_bounds__(256) void out_kernel(const float* __restrict__ Xs,
                                                  const float* __restrict__ cw,
                                                  const float* __restrict__ cb,
                                                  float* __restrict__ out) {
    __shared__ float h[NB * NH];
    __shared__ float cws[NT * NH];
    __shared__ float cbs[NT];
    const int n = blockIdx.x;
    const int t = threadIdx.x;
    for (int i = t; i < NT * NH; i += 256) cws[i] = cw[i];
    if (t < NT) cbs[t] = cb[t];
    for (int i = t; i < NB * NH; i += 256) {
        const int b = i >> 5, j = i & 31;
        h[i] = Xs[(size_t)n * COLP + b * CH + 1 + j];
    }
    __syncthreads();
    for (int p = t; p < NB * NT; p += 256) {
        const int b = p / NT, tt = p % NT;
        float acc = cbs[tt];
#pragma unroll
        for (int j = 0; j < NH; ++j) acc += h[b * NH + j] * cws[tt * NH + j];
        out[(size_t)b * NNODE * NT + (size_t)n * NT + tt] = acc;
    }
}

extern "C" void kernel_launch(void* const* d_in, const int* in_sizes, int n_in,
                              void* d_out, int out_size, void* d_ws, size_t ws_size,
                              hipStream_t stream) {
    const float* src  = (const float*)d_in[0];
    const float* E    = (const float*)d_in[1];
    const float* gW   = (const float*)d_in[2];
    const float* gb   = (const float*)d_in[3];
    const float* uW   = (const float*)d_in[4];
    const float* ub   = (const float*)d_in[5];
    const float* cw   = (const float*)d_in[6];
    const float* cb   = (const float*)d_in[7];
    float* out = (float*)d_out;

    float* ws = (float*)d_ws;
    _Float16* Ah = (_Float16*)(ws + OFF_AH);
    float* Wg  = ws + OFF_WG;
    float* Wu  = ws + OFF_WU;
    float* bg  = ws + OFF_BG;
    float* bu  = ws + OFF_BU;
    float* Xs  = ws + OFF_XS;
    float* Xs2 = ws + OFF_XS2;
    float* Y   = ws + OFF_Y;
    float* rb  = ws + OFF_R;

    adj_kernel<<<NNODE, 256, 0, stream>>>(E, Ah);
    wg_kernel<<<(NNODE * 4224 + 255) / 256, 256, 0, stream>>>(E, gW, Wg);
    wu_kernel<<<(NNODE * 2112 + 255) / 256, 256, 0, stream>>>(E, uW, Wu);
    bias_kernel<<<(NNODE * 96 + 255) / 256, 256, 0, stream>>>(E, gb, ub, bg, bu);
    setup_kernel<<<(NNODE * COLP + 255) / 256, 256, 0, stream>>>(src, Xs, Xs2);

    const dim3 mmgrid(COLP / 128, NNODE / 128);
    for (int t = 0; t < NT; ++t) {
        mm_kernel<<<mmgrid, 256, 0, stream>>>(Ah, Xs, Y);
        gate_kernel<<<NNODE, 256, 0, stream>>>(Xs, Y, Wg, bg, Xs2, rb);
        mm_kernel<<<mmgrid, 256, 0, stream>>>(Ah, Xs2, Y);
        upd_kernel<<<NNODE, 256, 0, stream>>>(Xs2, Y, Wu, bu, rb, src, Xs, t + 1);
    }
    out_kernel<<<NNODE, 256, 0, stream>>>(Xs, cw, cb, out);
}

// Round 4
// 1755.330 us; speedup vs baseline: 2.9336x; 1.4385x over previous
//
#include <hip/hip_runtime.h>
#include <hip/hip_bf16.h>
#include <math.h>

// Problem constants
// B=32, T=12, N=2048, C=1, D=10, K=2, H=32
// CH = C+H = 33, COLS = B*CH = 1056, padded to COLP = 1152 (=9*128)

#define NNODE 2048
#define NB 32
#define NT 12
#define NH 32
#define CH 33
#define COLS 1056
#define COLP 1152
#define ND 10

// A is stored fp16 pre-scaled by ASCALE (power of 2, exact) to keep softmax
// tail entries out of fp16-denormal range; mm epilogue multiplies by 1/ASCALE.
#define ASCALE 256.0f
#define AINV 0.00390625f

// split-K factor for mm: 2048 = 4 * 512 -> grid 9*16*4 = 576 blocks (2.25/CU)
#define KSPLIT 4
#define KCHUNK 512
#define YSTRIDE ((size_t)NNODE * COLP)  // one Y partial, in floats

typedef _Float16 half8 __attribute__((ext_vector_type(8)));
typedef float floatx4 __attribute__((ext_vector_type(4)));

// ---------------- workspace layout (in float slots) ----------------
constexpr size_t OFF_AH  = 0;                          // Ah fp16: 2048*2048 halfs = 2,097,152 slots
constexpr size_t OFF_WG  = OFF_AH + 2097152u;          // Wg fp16: 2048*4224 halfs = 4,325,376 slots
constexpr size_t OFF_WU  = OFF_WG + 4325376u;          // Wu fp16: 2048*2112 halfs = 2,162,688 slots
constexpr size_t OFF_BG  = OFF_WU + 2162688u;          // bg fp32: 2048*64
constexpr size_t OFF_BU  = OFF_BG + 131072u;           // bu fp32: 2048*32
constexpr size_t OFF_XS  = OFF_BU + 65536u;            // Xs:  2048*1152
constexpr size_t OFF_XS2 = OFF_XS + 2359296u;          // Xs2: 2048*1152
constexpr size_t OFF_Y   = OFF_XS2 + 2359296u;         // Y: 4 partials x 2048*1152
constexpr size_t OFF_R   = OFF_Y + 4u * 2359296u;      // rbuf: 2048*1024
// end = OFF_R + 2097152 = 25,034,752 floats = ~100.1 MB

static __device__ __forceinline__ unsigned short f2h(float f) {
    _Float16 h = (_Float16)f;
    return *(unsigned short*)&h;
}

// ---------------- A = softmax(relu(E E^T), axis=1) * ASCALE, stored fp16 ----------------
__global__ __launch_bounds__(256) void adj_kernel(const float* __restrict__ E,
                                                  _Float16* __restrict__ Ah) {
    __shared__ float En[ND];
    __shared__ float red[256];
    const int n = blockIdx.x;
    const int t = threadIdx.x;
    if (t < ND) En[t] = E[n * ND + t];
    __syncthreads();
    float v[8];
    float mx = 0.f;
#pragma unroll
    for (int i = 0; i < 8; ++i) {
        const int m = t + i * 256;
        float acc = 0.f;
#pragma unroll
        for (int d = 0; d < ND; ++d) acc += En[d] * E[m * ND + d];
        acc = fmaxf(acc, 0.f);
        v[i] = acc;
        mx = fmaxf(mx, acc);
    }
    red[t] = mx;
    __syncthreads();
    for (int s = 128; s > 0; s >>= 1) {
        if (t < s) red[t] = fmaxf(red[t], red[t + s]);
        __syncthreads();
    }
    mx = red[0];
    __syncthreads();
    float sum = 0.f;
#pragma unroll
    for (int i = 0; i < 8; ++i) {
        v[i] = expf(v[i] - mx);
        sum += v[i];
    }
    red[t] = sum;
    __syncthreads();
    for (int s = 128; s > 0; s >>= 1) {
        if (t < s) red[t] += red[t + s];
        __syncthreads();
    }
    const float inv = ASCALE / red[0];
#pragma unroll
    for (int i = 0; i < 8; ++i)
        Ah[(size_t)n * NNODE + t + i * 256] = (_Float16)(v[i] * inv);
}

// ---------------- per-node weights (stored fp16) ----------------
__global__ __launch_bounds__(256) void wg_kernel(const float* __restrict__ E,
                                                 const float* __restrict__ gW,
                                                 _Float16* __restrict__ Wg) {
    const int idx = blockIdx.x * 256 + threadIdx.x;
    if (idx >= NNODE * 4224) return;
    const int n = idx / 4224, rem = idx % 4224;
    float acc = 0.f;
#pragma unroll
    for (int d = 0; d < ND; ++d) acc += E[n * ND + d] * gW[d * 4224 + rem];
    Wg[idx] = (_Float16)acc;
}

__global__ __launch_bounds__(256) void wu_kernel(const float* __restrict__ E,
                                                 const float* __restrict__ uW,
                                                 _Float16* __restrict__ Wu) {
    const int idx = blockIdx.x * 256 + threadIdx.x;
    if (idx >= NNODE * 2112) return;
    const int n = idx / 2112, rem = idx % 2112;
    float acc = 0.f;
#pragma unroll
    for (int d = 0; d < ND; ++d) acc += E[n * ND + d] * uW[d * 2112 + rem];
    Wu[idx] = (_Float16)acc;
}

__global__ __launch_bounds__(256) void bias_kernel(const float* __restrict__ E,
                                                   const float* __restrict__ gb,
                                                   const float* __restrict__ ub,
                                                   float* __restrict__ bg,
                                                   float* __restrict__ bu) {
    const int idx = blockIdx.x * 256 + threadIdx.x;
    if (idx < NNODE * 64) {
        const int n = idx >> 6, o = idx & 63;
        float acc = 0.f;
#pragma unroll
        for (int d = 0; d < ND; ++d) acc += E[n * ND + d] * gb[d * 64 + o];
        bg[idx] = acc;
    } else if (idx < NNODE * 64 + NNODE * 32) {
        const int j = idx - NNODE * 64;
        const int n = j >> 5, o = j & 31;
        float acc = 0.f;
#pragma unroll
        for (int d = 0; d < ND; ++d) acc += E[n * ND + d] * ub[d * 32 + o];
        bu[j] = acc;
    }
}

// ---------------- init Xs (x cols = x_0, rest 0) and zero Xs2 ----------------
__global__ __launch_bounds__(256) void setup_kernel(const float* __restrict__ src,
                                                    float* __restrict__ Xs,
                                                    float* __restrict__ Xs2) {
    const int idx = blockIdx.x * 256 + threadIdx.x;
    if (idx >= NNODE * COLP) return;
    const int n = idx / COLP, c = idx % COLP;
    float v = 0.f;
    if (c < COLS && (c % CH) == 0) {
        const int b = c / CH;
        v = src[(size_t)b * NT * NNODE + n];  // t = 0
    }
    Xs[idx] = v;
    Xs2[idx] = 0.f;
}

// ---------------- Y_part[z] = (A*ASCALE)[:, zK:(z+1)K] @ X[zK:(z+1)K, :] * (1/ASCALE) ----------------
// A: fp16 [2048][2048] row-major (k-contig). X: fp32 [2048][COLP].
// Block tile 128(m) x 128(n) x Kchunk 512, BK=32. 4 waves, each 64x64.
// LDS rows padded to 40 halfs (80B = 20 dwords): 16B-aligned b128, uniform bank spread.
__global__ __launch_bounds__(256) void mm_kernel(const _Float16* __restrict__ Ah,
                                                 const float* __restrict__ X,
                                                 float* __restrict__ Y) {
    __shared__ unsigned short As[128][40];  // [m][k]
    __shared__ unsigned short Bs[128][40];  // [n][k] (transposed X tile)
    const int t = threadIdx.x;
    const int m0 = blockIdx.y * 128;
    const int c0 = blockIdx.x * 128;
    const int kz = blockIdx.z;
    float* __restrict__ Yp = Y + (size_t)kz * YSTRIDE;
    const int lane = t & 63;
    const int w = t >> 6;
    const int wm = (w & 1) * 64;
    const int wn = (w >> 1) * 64;
    const int lm = lane & 15;  // row/col within 16-tile
    const int q = lane >> 4;   // quad -> k-offset q*8

    // A staging: thread t handles row ar, 16-half chunk pair at ac
    const int ar = t >> 1;
    const int ac = (t & 1) * 16;
    // B staging: thread t handles k rows [4*bh,4*bh+4), col pairs 2*bu(+64)
    const int bu = t & 31;
    const int bh = t >> 5;

    floatx4 acc[4][4] = {};

    const int kend = kz * KCHUNK + KCHUNK;
    for (int kt = kz * KCHUNK; kt < kend; kt += 32) {
        // global loads first (let them overlap)
        const unsigned short* pa =
            (const unsigned short*)Ah + (size_t)(m0 + ar) * NNODE + kt + ac;
        uint4 a0 = *(const uint4*)pa;
        uint4 a1 = *(const uint4*)(pa + 8);
        float2 xv[4][2];
        const float* xb = X + (size_t)(kt + 4 * bh) * COLP + c0 + 2 * bu;
#pragma unroll
        for (int i = 0; i < 4; ++i) {
            xv[i][0] = *(const float2*)(xb + (size_t)i * COLP);
            xv[i][1] = *(const float2*)(xb + (size_t)i * COLP + 64);
        }
        *(uint4*)&As[ar][ac] = a0;
        *(uint4*)&As[ar][ac + 8] = a1;
#pragma unroll
        for (int j = 0; j < 2; ++j) {
#pragma unroll
            for (int cc = 0; cc < 2; ++cc) {
#pragma unroll
                for (int kp = 0; kp < 2; ++kp) {
                    const float f0 = cc ? xv[2 * kp][j].y : xv[2 * kp][j].x;
                    const float f1 = cc ? xv[2 * kp + 1][j].y : xv[2 * kp + 1][j].x;
                    const unsigned int pk =
                        (unsigned int)f2h(f0) | ((unsigned int)f2h(f1) << 16);
                    *(unsigned int*)&Bs[2 * bu + 64 * j + cc][4 * bh + 2 * kp] = pk;
                }
            }
        }
        __syncthreads();
        half8 af[4], bf[4];
#pragma unroll
        for (int mt = 0; mt < 4; ++mt)
            af[mt] = *(const half8*)&As[wm + mt * 16 + lm][q * 8];
#pragma unroll
        for (int nt = 0; nt < 4; ++nt)
            bf[nt] = *(const half8*)&Bs[wn + nt * 16 + lm][q * 8];
#pragma unroll
        for (int mt = 0; mt < 4; ++mt)
#pragma unroll
            for (int nt = 0; nt < 4; ++nt)
                acc[mt][nt] = __builtin_amdgcn_mfma_f32_16x16x32_f16(
                    af[mt], bf[nt], acc[mt][nt], 0, 0, 0);
        __syncthreads();
    }
    // epilogue: C/D layout col = lane&15, row = quad*4 + reg; undo ASCALE
#pragma unroll
    for (int mt = 0; mt < 4; ++mt) {
#pragma unroll
        for (int nt = 0; nt < 4; ++nt) {
            const int row = m0 + wm + mt * 16 + q * 4;
            const int col = c0 + wn + nt * 16 + lm;
#pragma unroll
            for (int r = 0; r < 4; ++r)
                Yp[(size_t)(row + r) * COLP + col] = acc[mt][nt][r] * AINV;
        }
    }
}

// ---------------- gate: zr = sigmoid(per-node W applied to [Xs | A@Xs]) ----------------
__global__ __launch_bounds__(256) void gate_kernel(const float* __restrict__ Xs,
                                                   const float* __restrict__ Y,
                                                   const _Float16* __restrict__ Wg,
                                                   const float* __restrict__ bg,
                                                   float* __restrict__ Xs2,
                                                   float* __restrict__ rbuf) {
    __shared__ float Wgs[4224];
    __shared__ float xrow[COLS];
    __shared__ float yrow[COLS];
    const int n = blockIdx.x;
    const int t = threadIdx.x;
    {
        const unsigned* wp = (const unsigned*)(Wg + (size_t)n * 4224);
        for (int i = t; i < 2112; i += 256) {
            union { unsigned u; _Float16 h[2]; } cv;
            cv.u = wp[i];
            Wgs[2 * i]     = (float)cv.h[0];
            Wgs[2 * i + 1] = (float)cv.h[1];
        }
    }
    const float* y0 = Y + (size_t)n * COLP;
    for (int i = t; i < COLS; i += 256) {
        xrow[i] = Xs[(size_t)n * COLP + i];
        yrow[i] = (y0[i] + y0[YSTRIDE + i]) + (y0[2 * YSTRIDE + i] + y0[3 * YSTRIDE + i]);
    }
    __syncthreads();
    const int o = t & 63;
    const int b0 = t >> 6;  // 0..3
#pragma unroll
    for (int bi = 0; bi < 8; ++bi) {
        const int b = b0 + bi * 4;
        float acc = bg[n * 64 + o];
        const float* xr = xrow + b * CH;
        const float* yr = yrow + b * CH;
#pragma unroll
        for (int i = 0; i < CH; ++i) {
            acc += xr[i] * Wgs[i * 64 + o];
            acc += yr[i] * Wgs[2112 + i * 64 + o];
        }
        const float s = 1.f / (1.f + expf(-acc));
        if (o < 32) {
            const float hold = xr[1 + o];
            Xs2[(size_t)n * COLP + b * CH + 1 + o] = s * hold;
            if (o == 0) Xs2[(size_t)n * COLP + b * CH] = xr[0];
        } else {
            rbuf[(size_t)n * 1024 + b * 32 + (o - 32)] = s;
        }
    }
}

// ---------------- update ----------------
__global__ __launch_bounds__(256) void upd_kernel(const float* __restrict__ Xs2,
                                                  const float* __restrict__ Y,
                                                  const _Float16* __restrict__ Wu,
                                                  const float* __restrict__ bu,
                                                  const float* __restrict__ rbuf,
                                                  const float* __restrict__ src,
                                                  float* __restrict__ Xs, int tnext) {
    __shared__ float Wus[2112];
    __shared__ float xrow[COLS];
    __shared__ float yrow[COLS];
    const int n = blockIdx.x;
    const int t = threadIdx.x;
    {
        const unsigned* wp = (const unsigned*)(Wu + (size_t)n * 2112);
        for (int i = t; i < 1056; i += 256) {
            union { unsigned u; _Float16 h[2]; } cv;
            cv.u = wp[i];
            Wus[2 * i]     = (float)cv.h[0];
            Wus[2 * i + 1] = (float)cv.h[1];
        }
    }
    const float* y0 = Y + (size_t)n * COLP;
    for (int i = t; i < COLS; i += 256) {
        xrow[i] = Xs2[(size_t)n * COLP + i];
        yrow[i] = (y0[i] + y0[YSTRIDE + i]) + (y0[2 * YSTRIDE + i] + y0[3 * YSTRIDE + i]);
    }
    __syncthreads();
    const int o = t & 31;
    const int b0 = t >> 5;  // 0..7
#pragma unroll
    for (int bi = 0; bi < 4; ++bi) {
        const int b = b0 + bi * 8;
        float acc = bu[n * 32 + o];
        const float* xr = xrow + b * CH;
        const float* yr = yrow + b * CH;
#pragma unroll
        for (int i = 0; i < CH; ++i) {
            acc += xr[i] * Wus[i * 32 + o];
            acc += yr[i] * Wus[1056 + i * 32 + o];
        }
        const float hc = tanhf(acc);
        const float r = rbuf[(size_t)n * 1024 + b * 32 + o];
        const size_t hidx = (size_t)n * COLP + b * CH + 1 + o;
        const float hold = Xs[hidx];
        Xs[hidx] = r * hold + (1.f - r) * hc;
        if (o == 0 && tnext < NT)
            Xs[(size_t)n * COLP + b * CH] =
                src[(size_t)b * NT * NNODE + (size_t)tnext * NNODE + n];
    }
}

// ---------------- out[b,0,n,t] = dot(h[b,n,:], convW[t,:]) + convb[t] ----------------
__global__ __launch_bounds__(256) void out_kernel(const float* __restrict__ Xs,
                                                  const float* __restrict__ cw,
                                                  const float* __restrict__ cb,
                                                  float* __restrict__ out) {
    __shared__ float h[NB * NH];
    __shared__ float cws[NT * NH];
    __shared__ float cbs[NT];
    const int n = blockIdx.x;
    const int t = threadIdx.x;
    for (int i = t; i < NT * NH; i += 256) cws[i] = cw[i];
    if (t < NT) cbs[t] = cb[t];
    for (int i = t; i < NB * NH; i += 256) {
        const int b = i >> 5, j = i & 31;
        h[i] = Xs[(size_t)n * COLP + b * CH + 1 + j];
    }
    __syncthreads();
    for (int p = t; p < NB * NT; p += 256) {
        const int b = p / NT, tt = p % NT;
        float acc = cbs[tt];
#pragma unroll
        for (int j = 0; j < NH; ++j) acc += h[b * NH + j] * cws[tt * NH + j];
        out[(size_t)b * NNODE * NT + (size_t)n * NT + tt] = acc;
    }
}

extern "C" void kernel_launch(void* const* d_in, const int* in_sizes, int n_in,
                              void* d_out, int out_size, void* d_ws, size_t ws_size,
                              hipStream_t stream) {
    const float* src  = (const float*)d_in[0];
    const float* E    = (const float*)d_in[1];
    const float* gW   = (const float*)d_in[2];
    const float* gb   = (const float*)d_in[3];
    const float* uW   = (const float*)d_in[4];
    const float* ub   = (const float*)d_in[5];
    const float* cw   = (const float*)d_in[6];
    const float* cb   = (const float*)d_in[7];
    float* out = (float*)d_out;

    float* ws = (float*)d_ws;
    _Float16* Ah = (_Float16*)(ws + OFF_AH);
    _Float16* Wg = (_Float16*)(ws + OFF_WG);
    _Float16* Wu = (_Float16*)(ws + OFF_WU);
    float* bg  = ws + OFF_BG;
    float* bu  = ws + OFF_BU;
    float* Xs  = ws + OFF_XS;
    float* Xs2 = ws + OFF_XS2;
    float* Y   = ws + OFF_Y;
    float* rb  = ws + OFF_R;

    adj_kernel<<<NNODE, 256, 0, stream>>>(E, Ah);
    wg_kernel<<<(NNODE * 4224 + 255) / 256, 256, 0, stream>>>(E, gW, Wg);
    wu_kernel<<<(NNODE * 2112 + 255) / 256, 256, 0, stream>>>(E, uW, Wu);
    bias_kernel<<<(NNODE * 96 + 255) / 256, 256, 0, stream>>>(E, gb, ub, bg, bu);
    setup_kernel<<<(NNODE * COLP + 255) / 256, 256, 0, stream>>>(src, Xs, Xs2);

    const dim3 mmgrid(COLP / 128, NNODE / 128, KSPLIT);
    for (int t = 0; t < NT; ++t) {
        mm_kernel<<<mmgrid, 256, 0, stream>>>(Ah, Xs, Y);
        gate_kernel<<<NNODE, 256, 0, stream>>>(Xs, Y, Wg, bg, Xs2, rb);
        mm_kernel<<<mmgrid, 256, 0, stream>>>(Ah, Xs2, Y);
        upd_kernel<<<NNODE, 256, 0, stream>>>(Xs2, Y, Wu, bu, rb, src, Xs, t + 1);
    }
    out_kernel<<<NNODE, 256, 0, stream>>>(Xs, cw, cb, out);
}